// Round 17
// baseline (179.937 us; speedup 1.0000x reference)
//
#include <hip/hip_runtime.h>

typedef _Float16 f16;
typedef f16   f16x2 __attribute__((ext_vector_type(2)));
typedef f16   f16x4 __attribute__((ext_vector_type(4)));
typedef f16   f16x8 __attribute__((ext_vector_type(8)));
typedef float f32x2 __attribute__((ext_vector_type(2)));
typedef float f32x4 __attribute__((ext_vector_type(4)));

#define LOG2E 1.44269504088896f

__device__ __forceinline__ float fast_exp(float x) {  // e^x
    return __builtin_amdgcn_exp2f(x * LOG2E);
}
__device__ __forceinline__ float silu_f(float x) {
    return x / (1.f + __builtin_amdgcn_exp2f(-LOG2E * x));
}
__device__ __forceinline__ float softplus_f(float x) {
    if (x > 16.f) return x;
    float e = __builtin_amdgcn_exp2f(x * LOG2E);
    return __builtin_amdgcn_logf(1.f + e) * 0.69314718056f;
}

// DPP-based sum (VALU pipe). ctrls: 0xB1 xor1, 0x4E xor2 (quad_perm).
#define DPP_ADD(x, ctrl) \
    ((x) + __int_as_float(__builtin_amdgcn_update_dpp(0, __float_as_int(x), (ctrl), 0xF, 0xF, true)))

__device__ __forceinline__ void gload_lds16(const void* g, void* l) {
    __builtin_amdgcn_global_load_lds((__attribute__((address_space(1))) void*)(g),
                                     (__attribute__((address_space(3))) void*)(l), 16, 0, 0);
}

// ---------------- fused f32->f16 convert (all 5 operands, one launch) ----------------
__global__ __launch_bounds__(256) void cvt_all(const float* __restrict__ hidden, const float* __restrict__ W_in,
                                               const float* __restrict__ W_out, const float* __restrict__ W_dt,
                                               const float* __restrict__ W_x,
                                               f16* __restrict__ h16, f16* __restrict__ Win16,
                                               f16* __restrict__ Wout16, f16* __restrict__ Wdt16,
                                               f16* __restrict__ Wx16) {
    int i = blockIdx.x * 256 + threadIdx.x;  // f32x4-quad index
    const float* src;
    f16* dst;
    int idx;
    if (i < 1048576) { src = hidden; dst = h16; idx = i; }
    else if (i < 2097152) { src = W_in; dst = Win16; idx = i - 1048576; }
    else if (i < 2621440) { src = W_out; dst = Wout16; idx = i - 2097152; }
    else if (i < 2654208) { src = W_dt; dst = Wdt16; idx = i - 2621440; }
    else {  // W_x (96,2048) -> padded (128,2048), rows 96..127 zero
        int q = i - 2654208;
        int r = q >> 9;  // 512 quads per row
        f32x4 v = {0.f, 0.f, 0.f, 0.f};
        if (r < 96) v = ((const f32x4*)W_x)[q];
        f16x4 o = {(f16)v[0], (f16)v[1], (f16)v[2], (f16)v[3]};
        ((f16x4*)Wx16)[q] = o;
        return;
    }
    f32x4 v = ((const f32x4*)src)[idx];
    f16x4 o = {(f16)v[0], (f16)v[1], (f16)v[2], (f16)v[3]};
    ((f16x4*)dst)[idx] = o;
}

// sum 8 split-K f16 partials -> proj f32 ; also emit dtlo16 (cols 0..63)
__global__ void reduce_proj(const f16* __restrict__ Pws, float* __restrict__ proj,
                            f16* __restrict__ dtlo) {
    int i = blockIdx.x * 256 + threadIdx.x;  // 4096*128/4 = 131072
    int m = i >> 5, c0 = (i & 31) * 4;
    f32x4 s = {0.f, 0.f, 0.f, 0.f};
#pragma unroll
    for (int z = 0; z < 8; z++) {
        f16x4 p = *(const f16x4*)(Pws + (size_t)z * 4096 * 128 + (size_t)m * 128 + c0);
        s += (f32x4){(float)p[0], (float)p[1], (float)p[2], (float)p[3]};
    }
    *(f32x4*)(proj + (size_t)m * 128 + c0) = s;
    if (c0 < 64) {
        f16x4 o = {(f16)s[0], (f16)s[1], (f16)s[2], (f16)s[3]};
        *(f16x4*)(dtlo + (size_t)m * 64 + c0) = o;
    }
}

// =====================================================================================
// 256x256 in_proj GEMM, 16 waves (1024 thr, 4Mx4N, 64x64/wave): ring-4 BK=32 slots,
// prefetch distance 3, counted vmcnt(4) (2 calls/tile).
// =====================================================================================
__global__ __launch_bounds__(1024) void gemm256(const f16* __restrict__ A, const f16* __restrict__ B,
                                                f16* __restrict__ C, int N, int K) {
    __shared__ f16 As[4][256 * 32];  // 4 x 16KB ring
    __shared__ f16 Bs[4][256 * 32];  // 4 x 16KB ring
    const int tid = threadIdx.x;
    const int w = tid >> 6, l = tid & 63;             // 16 waves
    const int wr = w >> 2, wc = w & 3;                // 4M x 4N waves
    const int lrow = l & 15, lkb = l >> 4;            // K-granule 0..3
    const int gpos = ((lkb ^ ((lrow >> 1) & 3)) * 8); // read-side swizzled granule
    // XCD swizzle (grid 16x16 = 256 blocks, 32 per XCD)
    const int bid = blockIdx.y * 16 + blockIdx.x;
    const int wg = (bid & 7) * 32 + (bid >> 3);
    const int mt = wg >> 4, nt = wg & 15;
    const int NT = K >> 5;  // 32 for K=1024

    f32x4 acc[4][4];
#pragma unroll
    for (int i = 0; i < 4; i++)
#pragma unroll
        for (int j = 0; j < 4; j++) acc[i][j] = (f32x4){0.f, 0.f, 0.f, 0.f};

    const int srow = w * 16 + (l >> 2);
    const int sgran = (l & 3) ^ ((l >> 3) & 3);
    const f16* Ag = A + (size_t)(mt * 256 + srow) * K + sgran * 8;
    const f16* Bg = B + (size_t)(nt * 256 + srow) * K + sgran * 8;

#define SCALL(s, kt, q)                                        \
    do {                                                       \
        if ((q) == 0) gload_lds16(Ag + (kt), &As[s][w * 512]); \
        if ((q) == 1) gload_lds16(Bg + (kt), &Bs[s][w * 512]); \
    } while (0)

    SCALL(0, 0, 0); SCALL(0, 0, 1);
    SCALL(1, 32, 0); SCALL(1, 32, 1);
    SCALL(2, 64, 0); SCALL(2, 64, 1);

    for (int t = 0; t < NT; ++t) {
        const f16* as = As[t & 3];
        const f16* bs = Bs[t & 3];
        const int pslot = (t + 3) & 3;
        const int pkt = ((t + 3 < NT) ? (t + 3) : (NT - 1)) * 32;

        asm volatile("s_waitcnt vmcnt(4)" ::: "memory");
        __builtin_amdgcn_sched_barrier(0);
        __builtin_amdgcn_s_barrier();
        __builtin_amdgcn_sched_barrier(0);

        f16x8 af[4], bf[4];
#pragma unroll
        for (int i = 0; i < 4; i++)
            af[i] = *(const f16x8*)&as[(wr * 64 + i * 16 + lrow) * 32 + gpos];
#pragma unroll
        for (int j = 0; j < 4; j++)
            bf[j] = *(const f16x8*)&bs[(wc * 64 + j * 16 + lrow) * 32 + gpos];
        SCALL(pslot, pkt, 0);
        SCALL(pslot, pkt, 1);
        __builtin_amdgcn_s_barrier();
        __builtin_amdgcn_sched_barrier(0);
        __builtin_amdgcn_s_setprio(1);
#pragma unroll
        for (int i = 0; i < 4; i++)
#pragma unroll
            for (int j = 0; j < 4; j++)
                acc[i][j] = __builtin_amdgcn_mfma_f32_16x16x32_f16(af[i], bf[j], acc[i][j], 0, 0, 0);
        __builtin_amdgcn_s_setprio(0);
    }
#undef SCALL

    const int orow = mt * 256 + wr * 64 + (l >> 4) * 4;
    const int ocol = nt * 256 + wc * 64 + lrow;
#pragma unroll
    for (int i = 0; i < 4; i++)
#pragma unroll
        for (int j = 0; j < 4; j++)
#pragma unroll
            for (int q = 0; q < 4; q++)
                C[(size_t)(orow + i * 16 + q) * N + ocol + j * 16] = (f16)acc[i][j][q];
}

// =====================================================================================
// out_proj GEMM: 128x128 tile, 8 waves, BK=32, ring-4 (64KB LDS -> 2 blocks/CU),
// prefetch distance 3, counted vmcnt(4).
// =====================================================================================
__global__ __launch_bounds__(512) void gemm_o32(const f16* __restrict__ A, const f16* __restrict__ B,
                                                float* __restrict__ C, int N, int K) {
    __shared__ f16 As[4][128 * 32];  // 4 x 8KB ring
    __shared__ f16 Bs[4][128 * 32];  // 4 x 8KB ring
    const int tid = threadIdx.x;
    const int w = tid >> 6, l = tid & 63;
    const int wr = w >> 2, wc = w & 3;                // 2M x 4N waves
    const int lrow = l & 15, lkb = l >> 4;
    const int gpos = ((lkb ^ ((lrow >> 1) & 3)) * 8);
    // XCD swizzle (grid 8x32 = 256 blocks, 32 per XCD)
    const int bid = blockIdx.y * 8 + blockIdx.x;
    const int wg = (bid & 7) * 32 + (bid >> 3);
    const int nt = wg & 7, mt = wg >> 3;
    const int NT = K >> 5;  // 64 for K=2048

    f32x4 acc[4][2];
#pragma unroll
    for (int i = 0; i < 4; i++)
#pragma unroll
        for (int j = 0; j < 2; j++) acc[i][j] = (f32x4){0.f, 0.f, 0.f, 0.f};

    const int srow = w * 16 + (l >> 2);
    const int sgran = (l & 3) ^ ((l >> 3) & 3);
    const f16* Ag = A + (size_t)(mt * 128 + srow) * K + sgran * 8;
    const f16* Bg = B + (size_t)(nt * 128 + srow) * K + sgran * 8;

#define QCALL(s, kt, q)                                        \
    do {                                                       \
        if ((q) == 0) gload_lds16(Ag + (kt), &As[s][w * 512]); \
        if ((q) == 1) gload_lds16(Bg + (kt), &Bs[s][w * 512]); \
    } while (0)

    QCALL(0, 0, 0); QCALL(0, 0, 1);
    QCALL(1, 32, 0); QCALL(1, 32, 1);
    QCALL(2, 64, 0); QCALL(2, 64, 1);

    for (int t = 0; t < NT; ++t) {
        const f16* as = As[t & 3];
        const f16* bs = Bs[t & 3];
        const int pslot = (t + 3) & 3;
        const int pkt = ((t + 3 < NT) ? (t + 3) : (NT - 1)) * 32;

        asm volatile("s_waitcnt vmcnt(4)" ::: "memory");
        __builtin_amdgcn_sched_barrier(0);
        __builtin_amdgcn_s_barrier();
        __builtin_amdgcn_sched_barrier(0);

        f16x8 af[4], bf[2];
#pragma unroll
        for (int i = 0; i < 4; i++)
            af[i] = *(const f16x8*)&as[(wr * 64 + i * 16 + lrow) * 32 + gpos];
#pragma unroll
        for (int j = 0; j < 2; j++)
            bf[j] = *(const f16x8*)&bs[(wc * 32 + j * 16 + lrow) * 32 + gpos];
        QCALL(pslot, pkt, 0);
        QCALL(pslot, pkt, 1);
        __builtin_amdgcn_s_barrier();
        __builtin_amdgcn_sched_barrier(0);
        __builtin_amdgcn_s_setprio(1);
#pragma unroll
        for (int i = 0; i < 4; i++)
#pragma unroll
            for (int j = 0; j < 2; j++)
                acc[i][j] = __builtin_amdgcn_mfma_f32_16x16x32_f16(af[i], bf[j], acc[i][j], 0, 0, 0);
        __builtin_amdgcn_s_setprio(0);
    }
#undef QCALL

    const int orow = mt * 128 + wr * 64 + (l >> 4) * 4;
    const int ocol = nt * 128 + wc * 32 + lrow;
#pragma unroll
    for (int i = 0; i < 4; i++)
#pragma unroll
        for (int j = 0; j < 2; j++)
#pragma unroll
            for (int q = 0; q < 4; q++)
                C[(size_t)(orow + i * 16 + q) * N + ocol + j * 16] = acc[i][j][q];
}

// ---------------- 128x128 GEMM (4 waves), BK=64, double-buffered, XOR-swizzled ----------------
template <int EPI, typename OutT>
__global__ __launch_bounds__(256) void gemm_gl(const f16* __restrict__ A, const f16* __restrict__ B,
                                               OutT* __restrict__ C, const float* __restrict__ bias,
                                               int M, int N, int K, int kstep) {
    __shared__ f16 As[2][128 * 64];  // 2 x 16KB
    __shared__ f16 Bs[2][128 * 64];
    const int tid = threadIdx.x;
    const int w = tid >> 6, l = tid & 63;
    const int wm = (w >> 1) * 64, wn = (w & 1) * 64;
    const int lrow = l & 15, lkb = l >> 4;
    const int swzr = lrow & 7;
    const int gx = gridDim.x;
    const int nwg = gx * gridDim.y;
    const int bid = blockIdx.y * gx + blockIdx.x;
    const int wg = (bid & 7) * (nwg >> 3) + (bid >> 3);
    const int nt = wg % gx, mt = wg / gx;
    const int kbeg = blockIdx.z * kstep;
    const int NT = kstep >> 6;
    OutT* Cz = C + (size_t)blockIdx.z * M * N;

    f32x4 acc[4][4];
#pragma unroll
    for (int i = 0; i < 4; i++)
#pragma unroll
        for (int j = 0; j < 4; j++) acc[i][j] = (f32x4){0.f, 0.f, 0.f, 0.f};

    const int srow = w * 32 + (l >> 3);
    const int sgran = (l & 7) ^ (l >> 3);
    const f16* Ag = A + (size_t)(mt * 128 + srow) * K + sgran * 8 + kbeg;
    const f16* Bg = B + (size_t)(nt * 128 + srow) * K + sgran * 8 + kbeg;

#define STAGE128(s, kt)                                                         \
    do {                                                                        \
        _Pragma("unroll")                                                       \
        for (int i = 0; i < 4; ++i) {                                           \
            gload_lds16(Ag + (size_t)(i * 8) * K + (kt), &As[s][(w * 32 + i * 8) * 64]); \
            gload_lds16(Bg + (size_t)(i * 8) * K + (kt), &Bs[s][(w * 32 + i * 8) * 64]); \
        }                                                                       \
    } while (0)

    STAGE128(0, 0);
    __syncthreads();

    int cur = 0;
    for (int t = 0; t < NT; ++t) {
        if (t + 1 < NT) STAGE128(cur ^ 1, (t + 1) * 64);
#pragma unroll
        for (int kk = 0; kk < 64; kk += 32) {
            f16x8 af[4], bf[4];
            const int g = (kk >> 3) + lkb;
#pragma unroll
            for (int i = 0; i < 4; i++) {
                af[i] = *(const f16x8*)&As[cur][(wm + i * 16 + lrow) * 64 + ((g ^ swzr) * 8)];
                bf[i] = *(const f16x8*)&Bs[cur][(wn + i * 16 + lrow) * 64 + ((g ^ swzr) * 8)];
            }
#pragma unroll
            for (int i = 0; i < 4; i++)
#pragma unroll
                for (int j = 0; j < 4; j++)
                    acc[i][j] = __builtin_amdgcn_mfma_f32_16x16x32_f16(af[i], bf[j], acc[i][j], 0, 0, 0);
        }
        __syncthreads();
        cur ^= 1;
    }
#undef STAGE128

    const int orow = mt * 128 + wm + (l >> 4) * 4;
    const int ocol = nt * 128 + wn + lrow;
#pragma unroll
    for (int fm = 0; fm < 4; fm++)
#pragma unroll
        for (int fn = 0; fn < 4; fn++) {
            int c = ocol + fn * 16;
            float bv = (EPI == 1) ? bias[c] : 0.f;
#pragma unroll
            for (int i = 0; i < 4; i++) {
                float v = acc[fm][fn][i];
                if (EPI == 1) v = softplus_f(v + bv);
                Cz[(size_t)(orow + fm * 16 + i) * N + c] = (OutT)v;
            }
        }
}

// ---------------- depthwise causal conv1d + SiLU, 4 timesteps/thread ----------------
__global__ __launch_bounds__(256) void conv_silu_k(const f16* __restrict__ xz, const float* __restrict__ cw,
                                                   const float* __restrict__ cb, f16* __restrict__ xc) {
    const int d0 = threadIdx.x * 8;
    const int g = blockIdx.x;                 // 1024 blocks
    const int b = g >> 9;
    const int l0 = (g & 511) * 4;
    const size_t mrow = (size_t)b * 2048 + l0;
    f32x4 cwv[8];
    float r0[8];
#pragma unroll
    for (int j = 0; j < 8; j++) {
        r0[j] = cb[d0 + j];
        cwv[j] = *(const f32x4*)(cw + (size_t)(d0 + j) * 4);
    }
    const f16x8 zero = {(f16)0.f, (f16)0.f, (f16)0.f, (f16)0.f, (f16)0.f, (f16)0.f, (f16)0.f, (f16)0.f};
    f16x8 xv[7];
#pragma unroll
    for (int i = 0; i < 7; ++i) {
        int ls = l0 - 3 + i;
        xv[i] = (ls >= 0) ? *(const f16x8*)(xz + (mrow - 3 + i) * 4096 + d0) : zero;
    }
#pragma unroll
    for (int tt = 0; tt < 4; ++tt) {
        float r[8];
#pragma unroll
        for (int j = 0; j < 8; j++) r[j] = r0[j];
#pragma unroll
        for (int k = 0; k < 4; k++)
#pragma unroll
            for (int j = 0; j < 8; j++) r[j] += cwv[j][k] * (float)xv[tt + k][j];
        f16x8 o;
#pragma unroll
        for (int j = 0; j < 8; j++) o[j] = (f16)silu_f(r[j]);
        *(f16x8*)(xc + (mrow + tt) * 2048 + d0) = o;
    }
}

// ---------------- chunked selective scan ----------------
// CT=32, NCHUNK=64. State buffers in NATURAL order (state i at slot i).
// p1: 1 lane = 1 chain (16 states in-lane; B broadcast; no reduce).
// p2: 4 lanes/chain, lane n owns states 4n..4n+3 (B+C reads amortized; quad DPP reduce).
#define CT 32
#define NCHUNK 64
#define NSTATE 65536  // 2*2048*16

__global__ __launch_bounds__(64) void scan_p1(const f16* __restrict__ dt16, const f16* __restrict__ xc,
                                              const float* __restrict__ proj, const float* __restrict__ A_log,
                                              f16* __restrict__ Pbuf, f16* __restrict__ Hend) {
    __shared__ float du_s[CT][66];  // packed f16x2 {dt, dt*x}; padded (stride 264B)
    __shared__ float bq_s[CT][16];  // B natural order
    const int l = threadIdx.x;
    const int c = blockIdx.x, dgb = blockIdx.y, b = blockIdx.z;
    const int d_base = dgb << 6;
    const int d = d_base + l;
    const size_t mb = (size_t)b * 2048 + (size_t)c * CT;

    float a[16];
#pragma unroll
    for (int i = 0; i < 16; i += 4) {
        f32x4 av = *(const f32x4*)(A_log + (size_t)d * 16 + i);
#pragma unroll
        for (int k = 0; k < 4; ++k) a[i + k] = -fast_exp(av[k]) * LOG2E;
    }
#pragma unroll
    for (int i = 0; i < 4; ++i) {
        int idx = i * 64 + l, row = idx >> 3, j0 = (idx & 7) * 8;
        size_t r = mb + row;
        f16x8 dt8 = *(const f16x8*)(dt16 + r * 2048 + d_base + j0);
        f16x8 xc8 = *(const f16x8*)(xc + r * 2048 + d_base + j0);
#pragma unroll
        for (int k = 0; k < 8; ++k) {
            union { f16x2 h2; float f; } u;
            u.h2[0] = dt8[k];
            u.h2[1] = (f16)((float)dt8[k] * (float)xc8[k]);
            du_s[row][j0 + k] = u.f;
        }
    }
#pragma unroll
    for (int i = 0; i < 2; ++i) {
        int idx = i * 64 + l, row = idx >> 2, s4 = (idx & 3) * 4;
        *(f32x4*)&bq_s[row][s4] = *(const f32x4*)(proj + (mb + row) * 128 + 64 + s4);
    }
    __syncthreads();

    float h[16];
#pragma unroll
    for (int i = 0; i < 16; ++i) h[i] = 0.f;
    float sdt = 0.f;
#pragma unroll 2
    for (int t = 0; t < CT; ++t) {
        union { float f; f16x2 h2; } u;
        u.f = du_s[t][l];
        float dtv = (float)u.h2[0], uv = (float)u.h2[1];
        sdt += dtv;
        f32x4 B0 = *(const f32x4*)&bq_s[t][0];
        f32x4 B1 = *(const f32x4*)&bq_s[t][4];
        f32x4 B2 = *(const f32x4*)&bq_s[t][8];
        f32x4 B3 = *(const f32x4*)&bq_s[t][12];
#pragma unroll
        for (int i = 0; i < 4; ++i) {
            h[i]      = fmaf(__builtin_amdgcn_exp2f(dtv * a[i]),      h[i],      uv * B0[i]);
            h[i + 4]  = fmaf(__builtin_amdgcn_exp2f(dtv * a[i + 4]),  h[i + 4],  uv * B1[i]);
            h[i + 8]  = fmaf(__builtin_amdgcn_exp2f(dtv * a[i + 8]),  h[i + 8],  uv * B2[i]);
            h[i + 12] = fmaf(__builtin_amdgcn_exp2f(dtv * a[i + 12]), h[i + 12], uv * B3[i]);
        }
    }
    const size_t base = (size_t)c * NSTATE + ((size_t)((b << 11) + d) << 4);
    f16x8 P0, P1, E0, E1;
#pragma unroll
    for (int i = 0; i < 8; ++i) {
        P0[i] = (f16)__builtin_amdgcn_exp2f(a[i] * sdt);
        P1[i] = (f16)__builtin_amdgcn_exp2f(a[i + 8] * sdt);
        E0[i] = (f16)h[i];
        E1[i] = (f16)h[i + 8];
    }
    *(f16x8*)(Pbuf + base) = P0;
    *(f16x8*)(Pbuf + base + 8) = P1;
    *(f16x8*)(Hend + base) = E0;
    *(f16x8*)(Hend + base + 8) = E1;
}

// Combine: f32 accumulation, f16 storage. 1 state per thread (order-agnostic).
__global__ __launch_bounds__(256) void scan_combine(const f16* __restrict__ Pbuf, const f16* __restrict__ Hend,
                                                    f16* __restrict__ Hinit) {
    int s = blockIdx.x * 256 + threadIdx.x;  // grid 256 blocks, 65536 states
    float h = 0.f;
#pragma unroll
    for (int c = 0; c < NCHUNK; c++) {
        size_t o = (size_t)c * NSTATE + s;
        Hinit[o] = (f16)h;
        h = fmaf((float)Pbuf[o], h, (float)Hend[o]);
    }
}

// p2: 4 states/lane, NATURAL order (lane n: states 4n..4n+3). 128 thr, 32 chains/block.
__global__ __launch_bounds__(128) void scan_p2(const f16* __restrict__ dt16, const f16* __restrict__ xc,
                                               const f16* __restrict__ xz, const float* __restrict__ proj,
                                               const float* __restrict__ A_log, const float* __restrict__ Dp,
                                               const f16* __restrict__ Hinit, f16* __restrict__ y16) {
    __shared__ f32x2 dg_s[CT][33];  // {pack(dt,u), pack(silu(z), D*x*silu(z))}; padded (264B stride)
    __shared__ float bq_s[CT][20];  // B natural (16 used + 4 pad)
    __shared__ float cq_s[CT][20];  // C natural
    const int tid = threadIdx.x;
    const int c = blockIdx.x, dg = blockIdx.y, b = blockIdx.z;
    const int d_base = dg << 5;
    const int g = tid >> 2, n = tid & 3;
    const int d = d_base + g;
    f32x4 av = *(const f32x4*)(A_log + (size_t)d * 16 + n * 4);
    const float a0 = -fast_exp(av[0]) * LOG2E;
    const float a1 = -fast_exp(av[1]) * LOG2E;
    const float a2 = -fast_exp(av[2]) * LOG2E;
    const float a3 = -fast_exp(av[3]) * LOG2E;
    const size_t mb = (size_t)b * 2048 + (size_t)c * CT;

    {   // staging: trow = tid>>2 (32 rows), seg = tid&3 (8 d's each)
        const int trow = tid >> 2, seg = tid & 3, j0 = seg * 8;
        const size_t row = mb + trow;
        f16x8 dt8 = *(const f16x8*)(dt16 + row * 2048 + d_base + j0);
        f16x8 xc8 = *(const f16x8*)(xc + row * 2048 + d_base + j0);
        f16x8 xz8 = *(const f16x8*)(xz + row * 4096 + 2048 + d_base + j0);
        f32x4 dv0 = *(const f32x4*)(Dp + d_base + j0);
        f32x4 dv1 = *(const f32x4*)(Dp + d_base + j0 + 4);
#pragma unroll
        for (int k = 0; k < 8; ++k) {
            float dtv = (float)dt8[k], xv = (float)xc8[k];
            union { f16x2 h2; float f; } u;
            u.h2[0] = dt8[k];
            u.h2[1] = (f16)(dtv * xv);
            float sz = silu_f((float)xz8[k]);
            float Dv = (k < 4) ? dv0[k & 3] : dv1[k & 3];
            union { f16x2 h2; float f; } v;
            v.h2[0] = (f16)sz;
            v.h2[1] = (f16)(Dv * xv * sz);
            dg_s[trow][j0 + k] = (f32x2){u.f, v.f};
        }
        // B/C natural order: thread -> row trow, quad seg
        *(f32x4*)&bq_s[trow][seg * 4] = *(const f32x4*)(proj + row * 128 + 64 + seg * 4);
        *(f32x4*)&cq_s[trow][seg * 4] = *(const f32x4*)(proj + row * 128 + 80 + seg * 4);
    }
    const size_t base = (size_t)c * NSTATE + ((size_t)((b << 11) + d) << 4) + n * 4;
    f16x4 H4 = *(const f16x4*)(Hinit + base);
    float h0 = (float)H4[0], h1 = (float)H4[1], h2 = (float)H4[2], h3 = (float)H4[3];
    __syncthreads();

#pragma unroll 8
    for (int t = 0; t < CT; ++t) {
        f32x2 dgv = dg_s[t][g];
        union { float f; f16x2 h2; } u;
        u.f = dgv[0];
        float dtv = (float)u.h2[0], uv = (float)u.h2[1];
        f32x4 B4 = *(const f32x4*)&bq_s[t][n * 4];
        f32x4 C4 = *(const f32x4*)&cq_s[t][n * 4];
        h0 = fmaf(__builtin_amdgcn_exp2f(dtv * a0), h0, uv * B4[0]);
        h1 = fmaf(__builtin_amdgcn_exp2f(dtv * a1), h1, uv * B4[1]);
        h2 = fmaf(__builtin_amdgcn_exp2f(dtv * a2), h2, uv * B4[2]);
        h3 = fmaf(__builtin_amdgcn_exp2f(dtv * a3), h3, uv * B4[3]);
        float yp = h0 * C4[0];
        yp = fmaf(h1, C4[1], yp);
        yp = fmaf(h2, C4[2], yp);
        yp = fmaf(h3, C4[3], yp);
        yp = DPP_ADD(yp, 0xB1);  // xor 1 within quad
        yp = DPP_ADD(yp, 0x4E);  // xor 2 within quad
        union { float f; f16x2 h2; } v;
        v.f = dgv[1];
        float yv = fmaf(yp, (float)v.h2[0], (float)v.h2[1]);
        if (n == 0) y16[(mb + t) * 2048 + d] = (f16)yv;
    }
}

extern "C" void kernel_launch(void* const* d_in, const int* in_sizes, int n_in,
                              void* d_out, int out_size, void* d_ws, size_t ws_size,
                              hipStream_t stream) {
    const float* hidden = (const float*)d_in[0];
    const float* W_in   = (const float*)d_in[1];
    const float* conv_w = (const float*)d_in[2];
    const float* conv_b = (const float*)d_in[3];
    const float* W_x    = (const float*)d_in[4];
    const float* W_dt   = (const float*)d_in[5];
    const float* b_dt   = (const float*)d_in[6];
    const float* A_log  = (const float*)d_in[7];
    const float* D_par  = (const float*)d_in[8];
    const float* W_out  = (const float*)d_in[9];
    float* out = (float*)d_out;

    char* ws = (char*)d_ws;
    size_t off = 0;
    auto alloc = [&](size_t bytes) { void* p = ws + off; off += (bytes + 255) & ~(size_t)255; return p; };
    f16* h16     = (f16*)alloc(4096ull * 1024 * 2);   // dead after in_proj -> Pbuf16
    f16* Win16   = (f16*)alloc(4096ull * 1024 * 2);   // dead after in_proj -> Hinit16
    f16* Wx16    = (f16*)alloc(128ull * 2048 * 2);
    f16* Wdt16   = (f16*)alloc(2048ull * 64 * 2);
    f16* Wout16  = (f16*)alloc(1024ull * 2048 * 2);
    f16* xz16    = (f16*)alloc(4096ull * 4096 * 2);
    f16* xc16    = (f16*)alloc(4096ull * 2048 * 2);
    float* proj  = (float*)alloc(4096ull * 128 * 4);
    f16* dtlo16  = (f16*)alloc(4096ull * 64 * 2);
    f16* dt16    = (f16*)alloc(4096ull * 2048 * 2);
    f16* y16     = (f16*)alloc(4096ull * 2048 * 2);   // 16.78MB
    // aliases (timeline-checked):
    f16* Pws     = (f16*)y16;     // f16 split-K partials (8.4MB): written/read before scan_p1
    f16* Pbuf16  = (f16*)h16;     // 8.39MB (h16 dead after in_proj)
    f16* Hend16  = (f16*)y16;     // 8.39MB; written by p1, read by combine, y16 rewritten in p2
    f16* Hinit16 = (f16*)Win16;   // 8.39MB (Win16 dead after in_proj)
    (void)ws_size; (void)in_sizes; (void)n_in; (void)out_size;

    // fused f32->f16 operand prep (one launch)
    cvt_all<<<10624, 256, 0, stream>>>(hidden, W_in, W_out, W_dt, W_x,
                                       h16, Win16, Wout16, Wdt16, Wx16);

    // in_proj: xz = hidden @ W_in^T   (4096 x 4096 x 1024) -- 16-wave gemm256
    gemm256<<<dim3(16, 16), 1024, 0, stream>>>(h16, Win16, xz16, 4096, 1024);
    // depthwise conv + SiLU (4 timesteps/thread)
    conv_silu_k<<<1024, 256, 0, stream>>>(xz16, conv_w, conv_b, xc16);
    // x_proj with split-K=8: Pws[z] = xc @ Wx^T over K-slice z (f16 partials)
    gemm_gl<0, f16><<<dim3(1, 32, 8), 256, 0, stream>>>(xc16, Wx16, Pws, nullptr, 4096, 128, 2048, 256);
    reduce_proj<<<512, 256, 0, stream>>>(Pws, proj, dtlo16);
    // dt = softplus(dtlo @ W_dt^T + b_dt) -> f16
    gemm_gl<1, f16><<<dim3(16, 32, 1), 256, 0, stream>>>(dtlo16, Wdt16, dt16, b_dt, 4096, 2048, 64, 64);
    // chunked selective scan + gating -> y16 (p1: 1 lane/chain; p2: 4 lanes/chain)
    scan_p1<<<dim3(NCHUNK, 32, 2), 64, 0, stream>>>(dt16, xc16, proj, A_log, Pbuf16, Hend16);
    scan_combine<<<256, 256, 0, stream>>>(Pbuf16, Hend16, Hinit16);
    scan_p2<<<dim3(NCHUNK, 64, 2), 128, 0, stream>>>(dt16, xc16, xz16, proj, A_log, D_par, Hinit16, y16);
    // out_proj: out = y @ W_out^T (BK=32 ring-4, 2 blocks/CU)
    gemm_o32<<<dim3(8, 32), 512, 0, stream>>>(y16, Wout16, out, 1024, 2048);
}

// Round 18
// 178.434 us; speedup vs baseline: 1.0084x; 1.0084x over previous
//
#include <hip/hip_runtime.h>

typedef _Float16 f16;
typedef f16   f16x2 __attribute__((ext_vector_type(2)));
typedef f16   f16x4 __attribute__((ext_vector_type(4)));
typedef f16   f16x8 __attribute__((ext_vector_type(8)));
typedef float f32x2 __attribute__((ext_vector_type(2)));
typedef float f32x4 __attribute__((ext_vector_type(4)));

#define LOG2E 1.44269504088896f

__device__ __forceinline__ float fast_exp(float x) {  // e^x
    return __builtin_amdgcn_exp2f(x * LOG2E);
}
__device__ __forceinline__ float silu_f(float x) {
    return x / (1.f + __builtin_amdgcn_exp2f(-LOG2E * x));
}
__device__ __forceinline__ float softplus_f(float x) {
    if (x > 16.f) return x;
    float e = __builtin_amdgcn_exp2f(x * LOG2E);
    return __builtin_amdgcn_logf(1.f + e) * 0.69314718056f;
}

// DPP-based sum (VALU pipe). ctrls: 0xB1 xor1, 0x4E xor2 (quad_perm).
#define DPP_ADD(x, ctrl) \
    ((x) + __int_as_float(__builtin_amdgcn_update_dpp(0, __float_as_int(x), (ctrl), 0xF, 0xF, true)))

__device__ __forceinline__ void gload_lds16(const void* g, void* l) {
    __builtin_amdgcn_global_load_lds((__attribute__((address_space(1))) void*)(g),
                                     (__attribute__((address_space(3))) void*)(l), 16, 0, 0);
}

// ---------------- fused f32->f16 convert (all 5 operands, one launch) ----------------
__global__ __launch_bounds__(256) void cvt_all(const float* __restrict__ hidden, const float* __restrict__ W_in,
                                               const float* __restrict__ W_out, const float* __restrict__ W_dt,
                                               const float* __restrict__ W_x,
                                               f16* __restrict__ h16, f16* __restrict__ Win16,
                                               f16* __restrict__ Wout16, f16* __restrict__ Wdt16,
                                               f16* __restrict__ Wx16) {
    int i = blockIdx.x * 256 + threadIdx.x;  // f32x4-quad index
    const float* src;
    f16* dst;
    int idx;
    if (i < 1048576) { src = hidden; dst = h16; idx = i; }
    else if (i < 2097152) { src = W_in; dst = Win16; idx = i - 1048576; }
    else if (i < 2621440) { src = W_out; dst = Wout16; idx = i - 2097152; }
    else if (i < 2654208) { src = W_dt; dst = Wdt16; idx = i - 2621440; }
    else {  // W_x (96,2048) -> padded (128,2048), rows 96..127 zero
        int q = i - 2654208;
        int r = q >> 9;  // 512 quads per row
        f32x4 v = {0.f, 0.f, 0.f, 0.f};
        if (r < 96) v = ((const f32x4*)W_x)[q];
        f16x4 o = {(f16)v[0], (f16)v[1], (f16)v[2], (f16)v[3]};
        ((f16x4*)Wx16)[q] = o;
        return;
    }
    f32x4 v = ((const f32x4*)src)[idx];
    f16x4 o = {(f16)v[0], (f16)v[1], (f16)v[2], (f16)v[3]};
    ((f16x4*)dst)[idx] = o;
}

// sum 8 split-K f16 partials -> proj f32 ; also emit dtlo16 (cols 0..63)
__global__ void reduce_proj(const f16* __restrict__ Pws, float* __restrict__ proj,
                            f16* __restrict__ dtlo) {
    int i = blockIdx.x * 256 + threadIdx.x;  // 4096*128/4 = 131072
    int m = i >> 5, c0 = (i & 31) * 4;
    f32x4 s = {0.f, 0.f, 0.f, 0.f};
#pragma unroll
    for (int z = 0; z < 8; z++) {
        f16x4 p = *(const f16x4*)(Pws + (size_t)z * 4096 * 128 + (size_t)m * 128 + c0);
        s += (f32x4){(float)p[0], (float)p[1], (float)p[2], (float)p[3]};
    }
    *(f32x4*)(proj + (size_t)m * 128 + c0) = s;
    if (c0 < 64) {
        f16x4 o = {(f16)s[0], (f16)s[1], (f16)s[2], (f16)s[3]};
        *(f16x4*)(dtlo + (size_t)m * 64 + c0) = o;
    }
}

// =====================================================================================
// 256x256 in_proj GEMM, 16 waves (1024 thr, 4Mx4N, 64x64/wave): ring-4 BK=32 slots,
// prefetch distance 3, counted vmcnt(4) (2 calls/tile).
// =====================================================================================
__global__ __launch_bounds__(1024) void gemm256(const f16* __restrict__ A, const f16* __restrict__ B,
                                                f16* __restrict__ C, int N, int K) {
    __shared__ f16 As[4][256 * 32];  // 4 x 16KB ring
    __shared__ f16 Bs[4][256 * 32];  // 4 x 16KB ring
    const int tid = threadIdx.x;
    const int w = tid >> 6, l = tid & 63;             // 16 waves
    const int wr = w >> 2, wc = w & 3;                // 4M x 4N waves
    const int lrow = l & 15, lkb = l >> 4;            // K-granule 0..3
    const int gpos = ((lkb ^ ((lrow >> 1) & 3)) * 8); // read-side swizzled granule
    // XCD swizzle (grid 16x16 = 256 blocks, 32 per XCD)
    const int bid = blockIdx.y * 16 + blockIdx.x;
    const int wg = (bid & 7) * 32 + (bid >> 3);
    const int mt = wg >> 4, nt = wg & 15;
    const int NT = K >> 5;  // 32 for K=1024

    f32x4 acc[4][4];
#pragma unroll
    for (int i = 0; i < 4; i++)
#pragma unroll
        for (int j = 0; j < 4; j++) acc[i][j] = (f32x4){0.f, 0.f, 0.f, 0.f};

    const int srow = w * 16 + (l >> 2);
    const int sgran = (l & 3) ^ ((l >> 3) & 3);
    const f16* Ag = A + (size_t)(mt * 256 + srow) * K + sgran * 8;
    const f16* Bg = B + (size_t)(nt * 256 + srow) * K + sgran * 8;

#define SCALL(s, kt, q)                                        \
    do {                                                       \
        if ((q) == 0) gload_lds16(Ag + (kt), &As[s][w * 512]); \
        if ((q) == 1) gload_lds16(Bg + (kt), &Bs[s][w * 512]); \
    } while (0)

    SCALL(0, 0, 0); SCALL(0, 0, 1);
    SCALL(1, 32, 0); SCALL(1, 32, 1);
    SCALL(2, 64, 0); SCALL(2, 64, 1);

    for (int t = 0; t < NT; ++t) {
        const f16* as = As[t & 3];
        const f16* bs = Bs[t & 3];
        const int pslot = (t + 3) & 3;
        const int pkt = ((t + 3 < NT) ? (t + 3) : (NT - 1)) * 32;

        asm volatile("s_waitcnt vmcnt(4)" ::: "memory");
        __builtin_amdgcn_sched_barrier(0);
        __builtin_amdgcn_s_barrier();
        __builtin_amdgcn_sched_barrier(0);

        f16x8 af[4], bf[4];
#pragma unroll
        for (int i = 0; i < 4; i++)
            af[i] = *(const f16x8*)&as[(wr * 64 + i * 16 + lrow) * 32 + gpos];
#pragma unroll
        for (int j = 0; j < 4; j++)
            bf[j] = *(const f16x8*)&bs[(wc * 64 + j * 16 + lrow) * 32 + gpos];
        SCALL(pslot, pkt, 0);
        SCALL(pslot, pkt, 1);
        __builtin_amdgcn_s_barrier();
        __builtin_amdgcn_sched_barrier(0);
        __builtin_amdgcn_s_setprio(1);
#pragma unroll
        for (int i = 0; i < 4; i++)
#pragma unroll
            for (int j = 0; j < 4; j++)
                acc[i][j] = __builtin_amdgcn_mfma_f32_16x16x32_f16(af[i], bf[j], acc[i][j], 0, 0, 0);
        __builtin_amdgcn_s_setprio(0);
    }
#undef SCALL

    const int orow = mt * 256 + wr * 64 + (l >> 4) * 4;
    const int ocol = nt * 256 + wc * 64 + lrow;
#pragma unroll
    for (int i = 0; i < 4; i++)
#pragma unroll
        for (int j = 0; j < 4; j++)
#pragma unroll
            for (int q = 0; q < 4; q++)
                C[(size_t)(orow + i * 16 + q) * N + ocol + j * 16] = (f16)acc[i][j][q];
}

// =====================================================================================
// out_proj GEMM: 128x128 tile, 8 waves, BK=32, ring-4 (64KB LDS -> 2 blocks/CU),
// prefetch distance 3, counted vmcnt(4).
// =====================================================================================
__global__ __launch_bounds__(512) void gemm_o32(const f16* __restrict__ A, const f16* __restrict__ B,
                                                float* __restrict__ C, int N, int K) {
    __shared__ f16 As[4][128 * 32];  // 4 x 8KB ring
    __shared__ f16 Bs[4][128 * 32];  // 4 x 8KB ring
    const int tid = threadIdx.x;
    const int w = tid >> 6, l = tid & 63;
    const int wr = w >> 2, wc = w & 3;                // 2M x 4N waves
    const int lrow = l & 15, lkb = l >> 4;
    const int gpos = ((lkb ^ ((lrow >> 1) & 3)) * 8);
    // XCD swizzle (grid 8x32 = 256 blocks, 32 per XCD)
    const int bid = blockIdx.y * 8 + blockIdx.x;
    const int wg = (bid & 7) * 32 + (bid >> 3);
    const int nt = wg & 7, mt = wg >> 3;
    const int NT = K >> 5;  // 64 for K=2048

    f32x4 acc[4][2];
#pragma unroll
    for (int i = 0; i < 4; i++)
#pragma unroll
        for (int j = 0; j < 2; j++) acc[i][j] = (f32x4){0.f, 0.f, 0.f, 0.f};

    const int srow = w * 16 + (l >> 2);
    const int sgran = (l & 3) ^ ((l >> 3) & 3);
    const f16* Ag = A + (size_t)(mt * 128 + srow) * K + sgran * 8;
    const f16* Bg = B + (size_t)(nt * 128 + srow) * K + sgran * 8;

#define QCALL(s, kt, q)                                        \
    do {                                                       \
        if ((q) == 0) gload_lds16(Ag + (kt), &As[s][w * 512]); \
        if ((q) == 1) gload_lds16(Bg + (kt), &Bs[s][w * 512]); \
    } while (0)

    QCALL(0, 0, 0); QCALL(0, 0, 1);
    QCALL(1, 32, 0); QCALL(1, 32, 1);
    QCALL(2, 64, 0); QCALL(2, 64, 1);

    for (int t = 0; t < NT; ++t) {
        const f16* as = As[t & 3];
        const f16* bs = Bs[t & 3];
        const int pslot = (t + 3) & 3;
        const int pkt = ((t + 3 < NT) ? (t + 3) : (NT - 1)) * 32;

        asm volatile("s_waitcnt vmcnt(4)" ::: "memory");
        __builtin_amdgcn_sched_barrier(0);
        __builtin_amdgcn_s_barrier();
        __builtin_amdgcn_sched_barrier(0);

        f16x8 af[4], bf[2];
#pragma unroll
        for (int i = 0; i < 4; i++)
            af[i] = *(const f16x8*)&as[(wr * 64 + i * 16 + lrow) * 32 + gpos];
#pragma unroll
        for (int j = 0; j < 2; j++)
            bf[j] = *(const f16x8*)&bs[(wc * 32 + j * 16 + lrow) * 32 + gpos];
        QCALL(pslot, pkt, 0);
        QCALL(pslot, pkt, 1);
        __builtin_amdgcn_s_barrier();
        __builtin_amdgcn_sched_barrier(0);
        __builtin_amdgcn_s_setprio(1);
#pragma unroll
        for (int i = 0; i < 4; i++)
#pragma unroll
            for (int j = 0; j < 2; j++)
                acc[i][j] = __builtin_amdgcn_mfma_f32_16x16x32_f16(af[i], bf[j], acc[i][j], 0, 0, 0);
        __builtin_amdgcn_s_setprio(0);
    }
#undef QCALL

    const int orow = mt * 128 + wr * 64 + (l >> 4) * 4;
    const int ocol = nt * 128 + wc * 32 + lrow;
#pragma unroll
    for (int i = 0; i < 4; i++)
#pragma unroll
        for (int j = 0; j < 2; j++)
#pragma unroll
            for (int q = 0; q < 4; q++)
                C[(size_t)(orow + i * 16 + q) * N + ocol + j * 16] = acc[i][j][q];
}

// ---------------- 128x128 GEMM (4 waves), BK=64, double-buffered, XOR-swizzled ----------------
template <int EPI, typename OutT>
__global__ __launch_bounds__(256) void gemm_gl(const f16* __restrict__ A, const f16* __restrict__ B,
                                               OutT* __restrict__ C, const float* __restrict__ bias,
                                               int M, int N, int K, int kstep) {
    __shared__ f16 As[2][128 * 64];  // 2 x 16KB
    __shared__ f16 Bs[2][128 * 64];
    const int tid = threadIdx.x;
    const int w = tid >> 6, l = tid & 63;
    const int wm = (w >> 1) * 64, wn = (w & 1) * 64;
    const int lrow = l & 15, lkb = l >> 4;
    const int swzr = lrow & 7;
    const int gx = gridDim.x;
    const int nwg = gx * gridDim.y;
    const int bid = blockIdx.y * gx + blockIdx.x;
    const int wg = (bid & 7) * (nwg >> 3) + (bid >> 3);
    const int nt = wg % gx, mt = wg / gx;
    const int kbeg = blockIdx.z * kstep;
    const int NT = kstep >> 6;
    OutT* Cz = C + (size_t)blockIdx.z * M * N;

    f32x4 acc[4][4];
#pragma unroll
    for (int i = 0; i < 4; i++)
#pragma unroll
        for (int j = 0; j < 4; j++) acc[i][j] = (f32x4){0.f, 0.f, 0.f, 0.f};

    const int srow = w * 32 + (l >> 3);
    const int sgran = (l & 7) ^ (l >> 3);
    const f16* Ag = A + (size_t)(mt * 128 + srow) * K + sgran * 8 + kbeg;
    const f16* Bg = B + (size_t)(nt * 128 + srow) * K + sgran * 8 + kbeg;

#define STAGE128(s, kt)                                                         \
    do {                                                                        \
        _Pragma("unroll")                                                       \
        for (int i = 0; i < 4; ++i) {                                           \
            gload_lds16(Ag + (size_t)(i * 8) * K + (kt), &As[s][(w * 32 + i * 8) * 64]); \
            gload_lds16(Bg + (size_t)(i * 8) * K + (kt), &Bs[s][(w * 32 + i * 8) * 64]); \
        }                                                                       \
    } while (0)

    STAGE128(0, 0);
    __syncthreads();

    int cur = 0;
    for (int t = 0; t < NT; ++t) {
        if (t + 1 < NT) STAGE128(cur ^ 1, (t + 1) * 64);
#pragma unroll
        for (int kk = 0; kk < 64; kk += 32) {
            f16x8 af[4], bf[4];
            const int g = (kk >> 3) + lkb;
#pragma unroll
            for (int i = 0; i < 4; i++) {
                af[i] = *(const f16x8*)&As[cur][(wm + i * 16 + lrow) * 64 + ((g ^ swzr) * 8)];
                bf[i] = *(const f16x8*)&Bs[cur][(wn + i * 16 + lrow) * 64 + ((g ^ swzr) * 8)];
            }
#pragma unroll
            for (int i = 0; i < 4; i++)
#pragma unroll
                for (int j = 0; j < 4; j++)
                    acc[i][j] = __builtin_amdgcn_mfma_f32_16x16x32_f16(af[i], bf[j], acc[i][j], 0, 0, 0);
        }
        __syncthreads();
        cur ^= 1;
    }
#undef STAGE128

    const int orow = mt * 128 + wm + (l >> 4) * 4;
    const int ocol = nt * 128 + wn + lrow;
#pragma unroll
    for (int fm = 0; fm < 4; fm++)
#pragma unroll
        for (int fn = 0; fn < 4; fn++) {
            int c = ocol + fn * 16;
            float bv = (EPI == 1) ? bias[c] : 0.f;
#pragma unroll
            for (int i = 0; i < 4; i++) {
                float v = acc[fm][fn][i];
                if (EPI == 1) v = softplus_f(v + bv);
                Cz[(size_t)(orow + fm * 16 + i) * N + c] = (OutT)v;
            }
        }
}

// ---------------- depthwise causal conv1d + SiLU, 4 timesteps/thread ----------------
__global__ __launch_bounds__(256) void conv_silu_k(const f16* __restrict__ xz, const float* __restrict__ cw,
                                                   const float* __restrict__ cb, f16* __restrict__ xc) {
    const int d0 = threadIdx.x * 8;
    const int g = blockIdx.x;                 // 1024 blocks
    const int b = g >> 9;
    const int l0 = (g & 511) * 4;
    const size_t mrow = (size_t)b * 2048 + l0;
    f32x4 cwv[8];
    float r0[8];
#pragma unroll
    for (int j = 0; j < 8; j++) {
        r0[j] = cb[d0 + j];
        cwv[j] = *(const f32x4*)(cw + (size_t)(d0 + j) * 4);
    }
    const f16x8 zero = {(f16)0.f, (f16)0.f, (f16)0.f, (f16)0.f, (f16)0.f, (f16)0.f, (f16)0.f, (f16)0.f};
    f16x8 xv[7];
#pragma unroll
    for (int i = 0; i < 7; ++i) {
        int ls = l0 - 3 + i;
        xv[i] = (ls >= 0) ? *(const f16x8*)(xz + (mrow - 3 + i) * 4096 + d0) : zero;
    }
#pragma unroll
    for (int tt = 0; tt < 4; ++tt) {
        float r[8];
#pragma unroll
        for (int j = 0; j < 8; j++) r[j] = r0[j];
#pragma unroll
        for (int k = 0; k < 4; k++)
#pragma unroll
            for (int j = 0; j < 8; j++) r[j] += cwv[j][k] * (float)xv[tt + k][j];
        f16x8 o;
#pragma unroll
        for (int j = 0; j < 8; j++) o[j] = (f16)silu_f(r[j]);
        *(f16x8*)(xc + (mrow + tt) * 2048 + d0) = o;
    }
}

// ---------------- chunked selective scan ----------------
// CT=32, NCHUNK=64. State buffers in PERMUTED order: slot j of a chain holds state
// perm(j) = (j&3)*4 + (j>>2) (4x4 transpose, involution). p1 (1 lane = 1 chain, 16
// states in-lane) permutes on store; p2 (4 lanes/chain, lane n owns states n,n+4,n+8,
// n+12 = slots 4n..4n+3) reads its f16x4 directly. combine is order-agnostic.
#define CT 32
#define NCHUNK 64
#define NSTATE 65536  // 2*2048*16

__global__ __launch_bounds__(64) void scan_p1(const f16* __restrict__ dt16, const f16* __restrict__ xc,
                                              const float* __restrict__ proj, const float* __restrict__ A_log,
                                              f16* __restrict__ Pbuf, f16* __restrict__ Hend) {
    __shared__ float du_s[CT][64];  // packed f16x2 {dt, dt*x}  8KB  (r16-measured layout)
    __shared__ float bq_s[CT][16];  // B natural order          2KB
    const int l = threadIdx.x;
    const int c = blockIdx.x, dgb = blockIdx.y, b = blockIdx.z;
    const int d_base = dgb << 6;
    const int d = d_base + l;
    const size_t mb = (size_t)b * 2048 + (size_t)c * CT;

    float a[16];
#pragma unroll
    for (int i = 0; i < 16; i += 4) {
        f32x4 av = *(const f32x4*)(A_log + (size_t)d * 16 + i);
#pragma unroll
        for (int k = 0; k < 4; ++k) a[i + k] = -fast_exp(av[k]) * LOG2E;
    }
#pragma unroll
    for (int i = 0; i < 4; ++i) {
        int idx = i * 64 + l, row = idx >> 3, j0 = (idx & 7) * 8;
        size_t r = mb + row;
        f16x8 dt8 = *(const f16x8*)(dt16 + r * 2048 + d_base + j0);
        f16x8 xc8 = *(const f16x8*)(xc + r * 2048 + d_base + j0);
#pragma unroll
        for (int k = 0; k < 8; ++k) {
            union { f16x2 h2; float f; } u;
            u.h2[0] = dt8[k];
            u.h2[1] = (f16)((float)dt8[k] * (float)xc8[k]);
            du_s[row][j0 + k] = u.f;
        }
    }
#pragma unroll
    for (int i = 0; i < 2; ++i) {
        int idx = i * 64 + l, row = idx >> 2, s4 = (idx & 3) * 4;
        *(f32x4*)&bq_s[row][s4] = *(const f32x4*)(proj + (mb + row) * 128 + 64 + s4);
    }
    __syncthreads();

    float h[16];
#pragma unroll
    for (int i = 0; i < 16; ++i) h[i] = 0.f;
    float sdt = 0.f;
#pragma unroll 2
    for (int t = 0; t < CT; ++t) {
        union { float f; f16x2 h2; } u;
        u.f = du_s[t][l];
        float dtv = (float)u.h2[0], uv = (float)u.h2[1];
        sdt += dtv;
        f32x4 B0 = *(const f32x4*)&bq_s[t][0];
        f32x4 B1 = *(const f32x4*)&bq_s[t][4];
        f32x4 B2 = *(const f32x4*)&bq_s[t][8];
        f32x4 B3 = *(const f32x4*)&bq_s[t][12];
#pragma unroll
        for (int i = 0; i < 4; ++i) {
            h[i]      = fmaf(__builtin_amdgcn_exp2f(dtv * a[i]),      h[i],      uv * B0[i]);
            h[i + 4]  = fmaf(__builtin_amdgcn_exp2f(dtv * a[i + 4]),  h[i + 4],  uv * B1[i]);
            h[i + 8]  = fmaf(__builtin_amdgcn_exp2f(dtv * a[i + 8]),  h[i + 8],  uv * B2[i]);
            h[i + 12] = fmaf(__builtin_amdgcn_exp2f(dtv * a[i + 12]), h[i + 12], uv * B3[i]);
        }
    }
    // store in PERMUTED slot order: slot j <- state (j&3)*4 + (j>>2)
    const size_t base = (size_t)c * NSTATE + ((size_t)((b << 11) + d) << 4);
    f16x8 P0, P1, E0, E1;
#pragma unroll
    for (int j = 0; j < 8; ++j) {
        const int s0 = ((j & 3) << 2) + (j >> 2);  // slots 0..7
        const int s1 = s0 + 2;                     // slots 8..15 (perm(j+8) = s0+2)
        P0[j] = (f16)__builtin_amdgcn_exp2f(a[s0] * sdt);
        P1[j] = (f16)__builtin_amdgcn_exp2f(a[s1] * sdt);
        E0[j] = (f16)h[s0];
        E1[j] = (f16)h[s1];
    }
    *(f16x8*)(Pbuf + base) = P0;
    *(f16x8*)(Pbuf + base + 8) = P1;
    *(f16x8*)(Hend + base) = E0;
    *(f16x8*)(Hend + base + 8) = E1;
}

// Combine: f32 accumulation, f16 storage. 1 state per thread (order-agnostic).
__global__ __launch_bounds__(256) void scan_combine(const f16* __restrict__ Pbuf, const f16* __restrict__ Hend,
                                                    f16* __restrict__ Hinit) {
    int s = blockIdx.x * 256 + threadIdx.x;  // grid 256 blocks, 65536 states
    float h = 0.f;
#pragma unroll
    for (int c = 0; c < NCHUNK; c++) {
        size_t o = (size_t)c * NSTATE + s;
        Hinit[o] = (f16)h;
        h = fmaf((float)Pbuf[o], h, (float)Hend[o]);
    }
}

// p2: 4 states/lane (r14-measured variant). Lane n owns states n, n+4, n+8, n+12
// (= permuted slots 4n..4n+3). 128 thr, 32 chains/block.
__global__ __launch_bounds__(128) void scan_p2(const f16* __restrict__ dt16, const f16* __restrict__ xc,
                                               const f16* __restrict__ xz, const float* __restrict__ proj,
                                               const float* __restrict__ A_log, const float* __restrict__ Dp,
                                               const f16* __restrict__ Hinit, f16* __restrict__ y16) {
    __shared__ f32x2 dg_s[CT][32];  // {pack(dt,u), pack(silu(z), D*x*silu(z))}  8KB
    __shared__ float bq_s[CT][20];  // B quad-permuted  2.5KB
    __shared__ float cq_s[CT][20];  // C quad-permuted  2.5KB
    const int tid = threadIdx.x;
    const int c = blockIdx.x, dg = blockIdx.y, b = blockIdx.z;
    const int d_base = dg << 5;
    const int g = tid >> 2, n = tid & 3;
    const int d = d_base + g;
    const float a0 = -fast_exp(A_log[d * 16 + n]) * LOG2E;
    const float a1 = -fast_exp(A_log[d * 16 + n + 4]) * LOG2E;
    const float a2 = -fast_exp(A_log[d * 16 + n + 8]) * LOG2E;
    const float a3 = -fast_exp(A_log[d * 16 + n + 12]) * LOG2E;
    const size_t mb = (size_t)b * 2048 + (size_t)c * CT;

    {   // staging: trow = tid>>2 (32 rows), seg = tid&3 (8 d's each)
        const int trow = tid >> 2, seg = tid & 3, j0 = seg * 8;
        const size_t row = mb + trow;
        f16x8 dt8 = *(const f16x8*)(dt16 + row * 2048 + d_base + j0);
        f16x8 xc8 = *(const f16x8*)(xc + row * 2048 + d_base + j0);
        f16x8 xz8 = *(const f16x8*)(xz + row * 4096 + 2048 + d_base + j0);
        f32x4 dv0 = *(const f32x4*)(Dp + d_base + j0);
        f32x4 dv1 = *(const f32x4*)(Dp + d_base + j0 + 4);
#pragma unroll
        for (int k = 0; k < 8; ++k) {
            float dtv = (float)dt8[k], xv = (float)xc8[k];
            union { f16x2 h2; float f; } u;
            u.h2[0] = dt8[k];
            u.h2[1] = (f16)(dtv * xv);
            float sz = silu_f((float)xz8[k]);
            float Dv = (k < 4) ? dv0[k & 3] : dv1[k & 3];
            union { f16x2 h2; float f; } v;
            v.h2[0] = (f16)sz;
            v.h2[1] = (f16)(Dv * xv * sz);
            dg_s[trow][j0 + k] = (f32x2){u.f, v.f};
        }
        f32x4 pb0 = *(const f32x4*)(proj + row * 128 + 64 + seg * 4);
        f32x4 pc0 = *(const f32x4*)(proj + row * 128 + 80 + seg * 4);
#pragma unroll
        for (int k = 0; k < 4; ++k) {
            bq_s[trow][k * 4 + seg] = pb0[k];   // slot (e&3)*4+(e>>2), e = seg*4+k
            cq_s[trow][k * 4 + seg] = pc0[k];
        }
    }
    const size_t base = (size_t)c * NSTATE + (size_t)(((b << 11) + d) * 16 + n * 4);
    f16x4 H4 = *(const f16x4*)(Hinit + base);
    float h0 = (float)H4[0], h1 = (float)H4[1], h2 = (float)H4[2], h3 = (float)H4[3];
    __syncthreads();

#pragma unroll 8
    for (int t = 0; t < CT; ++t) {
        f32x2 dgv = dg_s[t][g];
        union { float f; f16x2 h2; } u;
        u.f = dgv[0];
        float dtv = (float)u.h2[0], uv = (float)u.h2[1];
        f32x4 B4 = *(const f32x4*)&bq_s[t][n * 4];
        f32x4 C4 = *(const f32x4*)&cq_s[t][n * 4];
        h0 = fmaf(__builtin_amdgcn_exp2f(dtv * a0), h0, uv * B4[0]);
        h1 = fmaf(__builtin_amdgcn_exp2f(dtv * a1), h1, uv * B4[1]);
        h2 = fmaf(__builtin_amdgcn_exp2f(dtv * a2), h2, uv * B4[2]);
        h3 = fmaf(__builtin_amdgcn_exp2f(dtv * a3), h3, uv * B4[3]);
        float yp = h0 * C4[0];
        yp = fmaf(h1, C4[1], yp);
        yp = fmaf(h2, C4[2], yp);
        yp = fmaf(h3, C4[3], yp);
        yp = DPP_ADD(yp, 0xB1);  // xor 1 within quad
        yp = DPP_ADD(yp, 0x4E);  // xor 2 within quad
        union { float f; f16x2 h2; } v;
        v.f = dgv[1];
        float yv = fmaf(yp, (float)v.h2[0], (float)v.h2[1]);
        if (n == 0) y16[(mb + t) * 2048 + d] = (f16)yv;
    }
}

extern "C" void kernel_launch(void* const* d_in, const int* in_sizes, int n_in,
                              void* d_out, int out_size, void* d_ws, size_t ws_size,
                              hipStream_t stream) {
    const float* hidden = (const float*)d_in[0];
    const float* W_in   = (const float*)d_in[1];
    const float* conv_w = (const float*)d_in[2];
    const float* conv_b = (const float*)d_in[3];
    const float* W_x    = (const float*)d_in[4];
    const float* W_dt   = (const float*)d_in[5];
    const float* b_dt   = (const float*)d_in[6];
    const float* A_log  = (const float*)d_in[7];
    const float* D_par  = (const float*)d_in[8];
    const float* W_out  = (const float*)d_in[9];
    float* out = (float*)d_out;

    char* ws = (char*)d_ws;
    size_t off = 0;
    auto alloc = [&](size_t bytes) { void* p = ws + off; off += (bytes + 255) & ~(size_t)255; return p; };
    f16* h16     = (f16*)alloc(4096ull * 1024 * 2);   // dead after in_proj -> Pbuf16
    f16* Win16   = (f16*)alloc(4096ull * 1024 * 2);   // dead after in_proj -> Hinit16
    f16* Wx16    = (f16*)alloc(128ull * 2048 * 2);
    f16* Wdt16   = (f16*)alloc(2048ull * 64 * 2);
    f16* Wout16  = (f16*)alloc(1024ull * 2048 * 2);
    f16* xz16    = (f16*)alloc(4096ull * 4096 * 2);
    f16* xc16    = (f16*)alloc(4096ull * 2048 * 2);
    float* proj  = (float*)alloc(4096ull * 128 * 4);
    f16* dtlo16  = (f16*)alloc(4096ull * 64 * 2);
    f16* dt16    = (f16*)alloc(4096ull * 2048 * 2);
    f16* y16     = (f16*)alloc(4096ull * 2048 * 2);   // 16.78MB
    // aliases (timeline-checked):
    f16* Pws     = (f16*)y16;     // f16 split-K partials (8.4MB): written/read before scan_p1
    f16* Pbuf16  = (f16*)h16;     // 8.39MB (h16 dead after in_proj)
    f16* Hend16  = (f16*)y16;     // 8.39MB; written by p1, read by combine, y16 rewritten in p2
    f16* Hinit16 = (f16*)Win16;   // 8.39MB (Win16 dead after in_proj)
    (void)ws_size; (void)in_sizes; (void)n_in; (void)out_size;

    // fused f32->f16 operand prep (one launch)
    cvt_all<<<10624, 256, 0, stream>>>(hidden, W_in, W_out, W_dt, W_x,
                                       h16, Win16, Wout16, Wdt16, Wx16);

    // in_proj: xz = hidden @ W_in^T   (4096 x 4096 x 1024) -- 16-wave gemm256
    gemm256<<<dim3(16, 16), 1024, 0, stream>>>(h16, Win16, xz16, 4096, 1024);
    // depthwise conv + SiLU (4 timesteps/thread)
    conv_silu_k<<<1024, 256, 0, stream>>>(xz16, conv_w, conv_b, xc16);
    // x_proj with split-K=8: Pws[z] = xc @ Wx^T over K-slice z (f16 partials)
    gemm_gl<0, f16><<<dim3(1, 32, 8), 256, 0, stream>>>(xc16, Wx16, Pws, nullptr, 4096, 128, 2048, 256);
    reduce_proj<<<512, 256, 0, stream>>>(Pws, proj, dtlo16);
    // dt = softplus(dtlo @ W_dt^T + b_dt) -> f16
    gemm_gl<1, f16><<<dim3(16, 32, 1), 256, 0, stream>>>(dtlo16, Wdt16, dt16, b_dt, 4096, 2048, 64, 64);
    // chunked selective scan + gating -> y16 (p1: 1 lane/chain; p2: 4 lanes/chain)
    scan_p1<<<dim3(NCHUNK, 32, 2), 64, 0, stream>>>(dt16, xc16, proj, A_log, Pbuf16, Hend16);
    scan_combine<<<256, 256, 0, stream>>>(Pbuf16, Hend16, Hinit16);
    scan_p2<<<dim3(NCHUNK, 64, 2), 128, 0, stream>>>(dt16, xc16, xz16, proj, A_log, D_par, Hinit16, y16);
    // out_proj: out = y @ W_out^T (BK=32 ring-4, 2 blocks/CU)
    gemm_o32<<<dim3(8, 32), 512, 0, stream>>>(y16, Wout16, out, 1024, 2048);
}

// Round 19
// 175.470 us; speedup vs baseline: 1.0255x; 1.0169x over previous
//
#include <hip/hip_runtime.h>

typedef _Float16 f16;
typedef f16   f16x2 __attribute__((ext_vector_type(2)));
typedef f16   f16x4 __attribute__((ext_vector_type(4)));
typedef f16   f16x8 __attribute__((ext_vector_type(8)));
typedef float f32x2 __attribute__((ext_vector_type(2)));
typedef float f32x4 __attribute__((ext_vector_type(4)));

#define LOG2E 1.44269504088896f

__device__ __forceinline__ float fast_exp(float x) {  // e^x
    return __builtin_amdgcn_exp2f(x * LOG2E);
}
__device__ __forceinline__ float silu_f(float x) {
    return x / (1.f + __builtin_amdgcn_exp2f(-LOG2E * x));
}
__device__ __forceinline__ float softplus_f(float x) {
    if (x > 16.f) return x;
    float e = __builtin_amdgcn_exp2f(x * LOG2E);
    return __builtin_amdgcn_logf(1.f + e) * 0.69314718056f;
}

__device__ __forceinline__ void gload_lds16(const void* g, void* l) {
    __builtin_amdgcn_global_load_lds((__attribute__((address_space(1))) void*)(g),
                                     (__attribute__((address_space(3))) void*)(l), 16, 0, 0);
}

// ---------------- fused f32->f16 convert (all 5 operands, one launch) ----------------
__global__ __launch_bounds__(256) void cvt_all(const float* __restrict__ hidden, const float* __restrict__ W_in,
                                               const float* __restrict__ W_out, const float* __restrict__ W_dt,
                                               const float* __restrict__ W_x,
                                               f16* __restrict__ h16, f16* __restrict__ Win16,
                                               f16* __restrict__ Wout16, f16* __restrict__ Wdt16,
                                               f16* __restrict__ Wx16) {
    int i = blockIdx.x * 256 + threadIdx.x;  // f32x4-quad index
    const float* src;
    f16* dst;
    int idx;
    if (i < 1048576) { src = hidden; dst = h16; idx = i; }
    else if (i < 2097152) { src = W_in; dst = Win16; idx = i - 1048576; }
    else if (i < 2621440) { src = W_out; dst = Wout16; idx = i - 2097152; }
    else if (i < 2654208) { src = W_dt; dst = Wdt16; idx = i - 2621440; }
    else {  // W_x (96,2048) -> padded (128,2048), rows 96..127 zero
        int q = i - 2654208;
        int r = q >> 9;  // 512 quads per row
        f32x4 v = {0.f, 0.f, 0.f, 0.f};
        if (r < 96) v = ((const f32x4*)W_x)[q];
        f16x4 o = {(f16)v[0], (f16)v[1], (f16)v[2], (f16)v[3]};
        ((f16x4*)Wx16)[q] = o;
        return;
    }
    f32x4 v = ((const f32x4*)src)[idx];
    f16x4 o = {(f16)v[0], (f16)v[1], (f16)v[2], (f16)v[3]};
    ((f16x4*)dst)[idx] = o;
}

// sum 8 split-K f16 partials -> proj f32 ; also emit dtlo16 (cols 0..63)
__global__ void reduce_proj(const f16* __restrict__ Pws, float* __restrict__ proj,
                            f16* __restrict__ dtlo) {
    int i = blockIdx.x * 256 + threadIdx.x;  // 4096*128/4 = 131072
    int m = i >> 5, c0 = (i & 31) * 4;
    f32x4 s = {0.f, 0.f, 0.f, 0.f};
#pragma unroll
    for (int z = 0; z < 8; z++) {
        f16x4 p = *(const f16x4*)(Pws + (size_t)z * 4096 * 128 + (size_t)m * 128 + c0);
        s += (f32x4){(float)p[0], (float)p[1], (float)p[2], (float)p[3]};
    }
    *(f32x4*)(proj + (size_t)m * 128 + c0) = s;
    if (c0 < 64) {
        f16x4 o = {(f16)s[0], (f16)s[1], (f16)s[2], (f16)s[3]};
        *(f16x4*)(dtlo + (size_t)m * 64 + c0) = o;
    }
}

// =====================================================================================
// 256x256 in_proj GEMM, 16 waves (1024 thr, 4Mx4N, 64x64/wave): ring-4 BK=32 slots,
// prefetch distance 3, counted vmcnt(4) (2 calls/tile).
// =====================================================================================
__global__ __launch_bounds__(1024) void gemm256(const f16* __restrict__ A, const f16* __restrict__ B,
                                                f16* __restrict__ C, int N, int K) {
    __shared__ f16 As[4][256 * 32];  // 4 x 16KB ring
    __shared__ f16 Bs[4][256 * 32];  // 4 x 16KB ring
    const int tid = threadIdx.x;
    const int w = tid >> 6, l = tid & 63;             // 16 waves
    const int wr = w >> 2, wc = w & 3;                // 4M x 4N waves
    const int lrow = l & 15, lkb = l >> 4;            // K-granule 0..3
    const int gpos = ((lkb ^ ((lrow >> 1) & 3)) * 8); // read-side swizzled granule
    // XCD swizzle (grid 16x16 = 256 blocks, 32 per XCD)
    const int bid = blockIdx.y * 16 + blockIdx.x;
    const int wg = (bid & 7) * 32 + (bid >> 3);
    const int mt = wg >> 4, nt = wg & 15;
    const int NT = K >> 5;  // 32 for K=1024

    f32x4 acc[4][4];
#pragma unroll
    for (int i = 0; i < 4; i++)
#pragma unroll
        for (int j = 0; j < 4; j++) acc[i][j] = (f32x4){0.f, 0.f, 0.f, 0.f};

    const int srow = w * 16 + (l >> 2);
    const int sgran = (l & 3) ^ ((l >> 3) & 3);
    const f16* Ag = A + (size_t)(mt * 256 + srow) * K + sgran * 8;
    const f16* Bg = B + (size_t)(nt * 256 + srow) * K + sgran * 8;

#define SCALL(s, kt, q)                                        \
    do {                                                       \
        if ((q) == 0) gload_lds16(Ag + (kt), &As[s][w * 512]); \
        if ((q) == 1) gload_lds16(Bg + (kt), &Bs[s][w * 512]); \
    } while (0)

    SCALL(0, 0, 0); SCALL(0, 0, 1);
    SCALL(1, 32, 0); SCALL(1, 32, 1);
    SCALL(2, 64, 0); SCALL(2, 64, 1);

    for (int t = 0; t < NT; ++t) {
        const f16* as = As[t & 3];
        const f16* bs = Bs[t & 3];
        const int pslot = (t + 3) & 3;
        const int pkt = ((t + 3 < NT) ? (t + 3) : (NT - 1)) * 32;

        asm volatile("s_waitcnt vmcnt(4)" ::: "memory");
        __builtin_amdgcn_sched_barrier(0);
        __builtin_amdgcn_s_barrier();
        __builtin_amdgcn_sched_barrier(0);

        f16x8 af[4], bf[4];
#pragma unroll
        for (int i = 0; i < 4; i++)
            af[i] = *(const f16x8*)&as[(wr * 64 + i * 16 + lrow) * 32 + gpos];
#pragma unroll
        for (int j = 0; j < 4; j++)
            bf[j] = *(const f16x8*)&bs[(wc * 64 + j * 16 + lrow) * 32 + gpos];
        SCALL(pslot, pkt, 0);
        SCALL(pslot, pkt, 1);
        __builtin_amdgcn_s_barrier();
        __builtin_amdgcn_sched_barrier(0);
        __builtin_amdgcn_s_setprio(1);
#pragma unroll
        for (int i = 0; i < 4; i++)
#pragma unroll
            for (int j = 0; j < 4; j++)
                acc[i][j] = __builtin_amdgcn_mfma_f32_16x16x32_f16(af[i], bf[j], acc[i][j], 0, 0, 0);
        __builtin_amdgcn_s_setprio(0);
    }
#undef SCALL

    const int orow = mt * 256 + wr * 64 + (l >> 4) * 4;
    const int ocol = nt * 256 + wc * 64 + lrow;
#pragma unroll
    for (int i = 0; i < 4; i++)
#pragma unroll
        for (int j = 0; j < 4; j++)
#pragma unroll
            for (int q = 0; q < 4; q++)
                C[(size_t)(orow + i * 16 + q) * N + ocol + j * 16] = (f16)acc[i][j][q];
}

// =====================================================================================
// out_proj GEMM: 128x128 tile, 8 waves, BK=32, ring-4 (64KB LDS -> 2 blocks/CU),
// prefetch distance 3, counted vmcnt(4).
// =====================================================================================
__global__ __launch_bounds__(512) void gemm_o32(const f16* __restrict__ A, const f16* __restrict__ B,
                                                float* __restrict__ C, int N, int K) {
    __shared__ f16 As[4][128 * 32];  // 4 x 8KB ring
    __shared__ f16 Bs[4][128 * 32];  // 4 x 8KB ring
    const int tid = threadIdx.x;
    const int w = tid >> 6, l = tid & 63;
    const int wr = w >> 2, wc = w & 3;                // 2M x 4N waves
    const int lrow = l & 15, lkb = l >> 4;
    const int gpos = ((lkb ^ ((lrow >> 1) & 3)) * 8);
    // XCD swizzle (grid 8x32 = 256 blocks, 32 per XCD)
    const int bid = blockIdx.y * 8 + blockIdx.x;
    const int wg = (bid & 7) * 32 + (bid >> 3);
    const int nt = wg & 7, mt = wg >> 3;
    const int NT = K >> 5;  // 64 for K=2048

    f32x4 acc[4][2];
#pragma unroll
    for (int i = 0; i < 4; i++)
#pragma unroll
        for (int j = 0; j < 2; j++) acc[i][j] = (f32x4){0.f, 0.f, 0.f, 0.f};

    const int srow = w * 16 + (l >> 2);
    const int sgran = (l & 3) ^ ((l >> 3) & 3);
    const f16* Ag = A + (size_t)(mt * 128 + srow) * K + sgran * 8;
    const f16* Bg = B + (size_t)(nt * 128 + srow) * K + sgran * 8;

#define QCALL(s, kt, q)                                        \
    do {                                                       \
        if ((q) == 0) gload_lds16(Ag + (kt), &As[s][w * 512]); \
        if ((q) == 1) gload_lds16(Bg + (kt), &Bs[s][w * 512]); \
    } while (0)

    QCALL(0, 0, 0); QCALL(0, 0, 1);
    QCALL(1, 32, 0); QCALL(1, 32, 1);
    QCALL(2, 64, 0); QCALL(2, 64, 1);

    for (int t = 0; t < NT; ++t) {
        const f16* as = As[t & 3];
        const f16* bs = Bs[t & 3];
        const int pslot = (t + 3) & 3;
        const int pkt = ((t + 3 < NT) ? (t + 3) : (NT - 1)) * 32;

        asm volatile("s_waitcnt vmcnt(4)" ::: "memory");
        __builtin_amdgcn_sched_barrier(0);
        __builtin_amdgcn_s_barrier();
        __builtin_amdgcn_sched_barrier(0);

        f16x8 af[4], bf[2];
#pragma unroll
        for (int i = 0; i < 4; i++)
            af[i] = *(const f16x8*)&as[(wr * 64 + i * 16 + lrow) * 32 + gpos];
#pragma unroll
        for (int j = 0; j < 2; j++)
            bf[j] = *(const f16x8*)&bs[(wc * 32 + j * 16 + lrow) * 32 + gpos];
        QCALL(pslot, pkt, 0);
        QCALL(pslot, pkt, 1);
        __builtin_amdgcn_s_barrier();
        __builtin_amdgcn_sched_barrier(0);
        __builtin_amdgcn_s_setprio(1);
#pragma unroll
        for (int i = 0; i < 4; i++)
#pragma unroll
            for (int j = 0; j < 2; j++)
                acc[i][j] = __builtin_amdgcn_mfma_f32_16x16x32_f16(af[i], bf[j], acc[i][j], 0, 0, 0);
        __builtin_amdgcn_s_setprio(0);
    }
#undef QCALL

    const int orow = mt * 128 + wr * 64 + (l >> 4) * 4;
    const int ocol = nt * 128 + wc * 32 + lrow;
#pragma unroll
    for (int i = 0; i < 4; i++)
#pragma unroll
        for (int j = 0; j < 2; j++)
#pragma unroll
            for (int q = 0; q < 4; q++)
                C[(size_t)(orow + i * 16 + q) * N + ocol + j * 16] = acc[i][j][q];
}

// ---------------- 128x128 GEMM (4 waves), BK=64, double-buffered, XOR-swizzled ----------------
template <int EPI, typename OutT>
__global__ __launch_bounds__(256) void gemm_gl(const f16* __restrict__ A, const f16* __restrict__ B,
                                               OutT* __restrict__ C, const float* __restrict__ bias,
                                               int M, int N, int K, int kstep) {
    __shared__ f16 As[2][128 * 64];  // 2 x 16KB
    __shared__ f16 Bs[2][128 * 64];
    const int tid = threadIdx.x;
    const int w = tid >> 6, l = tid & 63;
    const int wm = (w >> 1) * 64, wn = (w & 1) * 64;
    const int lrow = l & 15, lkb = l >> 4;
    const int swzr = lrow & 7;
    const int gx = gridDim.x;
    const int nwg = gx * gridDim.y;
    const int bid = blockIdx.y * gx + blockIdx.x;
    const int wg = (bid & 7) * (nwg >> 3) + (bid >> 3);
    const int nt = wg % gx, mt = wg / gx;
    const int kbeg = blockIdx.z * kstep;
    const int NT = kstep >> 6;
    OutT* Cz = C + (size_t)blockIdx.z * M * N;

    f32x4 acc[4][4];
#pragma unroll
    for (int i = 0; i < 4; i++)
#pragma unroll
        for (int j = 0; j < 4; j++) acc[i][j] = (f32x4){0.f, 0.f, 0.f, 0.f};

    const int srow = w * 32 + (l >> 3);
    const int sgran = (l & 7) ^ (l >> 3);
    const f16* Ag = A + (size_t)(mt * 128 + srow) * K + sgran * 8 + kbeg;
    const f16* Bg = B + (size_t)(nt * 128 + srow) * K + sgran * 8 + kbeg;

#define STAGE128(s, kt)                                                         \
    do {                                                                        \
        _Pragma("unroll")                                                       \
        for (int i = 0; i < 4; ++i) {                                           \
            gload_lds16(Ag + (size_t)(i * 8) * K + (kt), &As[s][(w * 32 + i * 8) * 64]); \
            gload_lds16(Bg + (size_t)(i * 8) * K + (kt), &Bs[s][(w * 32 + i * 8) * 64]); \
        }                                                                       \
    } while (0)

    STAGE128(0, 0);
    __syncthreads();

    int cur = 0;
    for (int t = 0; t < NT; ++t) {
        if (t + 1 < NT) STAGE128(cur ^ 1, (t + 1) * 64);
#pragma unroll
        for (int kk = 0; kk < 64; kk += 32) {
            f16x8 af[4], bf[4];
            const int g = (kk >> 3) + lkb;
#pragma unroll
            for (int i = 0; i < 4; i++) {
                af[i] = *(const f16x8*)&As[cur][(wm + i * 16 + lrow) * 64 + ((g ^ swzr) * 8)];
                bf[i] = *(const f16x8*)&Bs[cur][(wn + i * 16 + lrow) * 64 + ((g ^ swzr) * 8)];
            }
#pragma unroll
            for (int i = 0; i < 4; i++)
#pragma unroll
                for (int j = 0; j < 4; j++)
                    acc[i][j] = __builtin_amdgcn_mfma_f32_16x16x32_f16(af[i], bf[j], acc[i][j], 0, 0, 0);
        }
        __syncthreads();
        cur ^= 1;
    }
#undef STAGE128

    const int orow = mt * 128 + wm + (l >> 4) * 4;
    const int ocol = nt * 128 + wn + lrow;
#pragma unroll
    for (int fm = 0; fm < 4; fm++)
#pragma unroll
        for (int fn = 0; fn < 4; fn++) {
            int c = ocol + fn * 16;
            float bv = (EPI == 1) ? bias[c] : 0.f;
#pragma unroll
            for (int i = 0; i < 4; i++) {
                float v = acc[fm][fn][i];
                if (EPI == 1) v = softplus_f(v + bv);
                Cz[(size_t)(orow + fm * 16 + i) * N + c] = (OutT)v;
            }
        }
}

// ---------------- depthwise causal conv1d + SiLU, 4 timesteps/thread ----------------
__global__ __launch_bounds__(256) void conv_silu_k(const f16* __restrict__ xz, const float* __restrict__ cw,
                                                   const float* __restrict__ cb, f16* __restrict__ xc) {
    const int d0 = threadIdx.x * 8;
    const int g = blockIdx.x;                 // 1024 blocks
    const int b = g >> 9;
    const int l0 = (g & 511) * 4;
    const size_t mrow = (size_t)b * 2048 + l0;
    f32x4 cwv[8];
    float r0[8];
#pragma unroll
    for (int j = 0; j < 8; j++) {
        r0[j] = cb[d0 + j];
        cwv[j] = *(const f32x4*)(cw + (size_t)(d0 + j) * 4);
    }
    const f16x8 zero = {(f16)0.f, (f16)0.f, (f16)0.f, (f16)0.f, (f16)0.f, (f16)0.f, (f16)0.f, (f16)0.f};
    f16x8 xv[7];
#pragma unroll
    for (int i = 0; i < 7; ++i) {
        int ls = l0 - 3 + i;
        xv[i] = (ls >= 0) ? *(const f16x8*)(xz + (mrow - 3 + i) * 4096 + d0) : zero;
    }
#pragma unroll
    for (int tt = 0; tt < 4; ++tt) {
        float r[8];
#pragma unroll
        for (int j = 0; j < 8; j++) r[j] = r0[j];
#pragma unroll
        for (int k = 0; k < 4; k++)
#pragma unroll
            for (int j = 0; j < 8; j++) r[j] += cwv[j][k] * (float)xv[tt + k][j];
        f16x8 o;
#pragma unroll
        for (int j = 0; j < 8; j++) o[j] = (f16)silu_f(r[j]);
        *(f16x8*)(xc + (mrow + tt) * 2048 + d0) = o;
    }
}

// ---------------- chunked selective scan: 1 lane = 1 (b,d) chain (16 states in-lane) ----
// CT=32, NCHUNK=64. 64-thr blocks; block covers 64 d's. B/C are LDS broadcast reads
// (shared by all chains); C.h dot is in-lane (no cross-lane reduce); y-store coalesced.
#define CT 32
#define NCHUNK 64
#define NSTATE 65536  // 2*2048*16

__global__ __launch_bounds__(64) void scan_p1(const f16* __restrict__ dt16, const f16* __restrict__ xc,
                                              const float* __restrict__ proj, const float* __restrict__ A_log,
                                              f16* __restrict__ Pbuf, f16* __restrict__ Hend) {
    __shared__ float du_s[CT][64];  // packed f16x2 {dt, dt*x}  8KB
    __shared__ float bq_s[CT][16];  // B natural order          2KB
    const int l = threadIdx.x;
    const int c = blockIdx.x, dgb = blockIdx.y, b = blockIdx.z;
    const int d_base = dgb << 6;
    const int d = d_base + l;
    const size_t mb = (size_t)b * 2048 + (size_t)c * CT;

    float a[16];
#pragma unroll
    for (int i = 0; i < 16; i += 4) {
        f32x4 av = *(const f32x4*)(A_log + (size_t)d * 16 + i);
#pragma unroll
        for (int k = 0; k < 4; ++k) a[i + k] = -fast_exp(av[k]) * LOG2E;
    }
    // staging: 4 iters x (8 d's of one row)
#pragma unroll
    for (int i = 0; i < 4; ++i) {
        int idx = i * 64 + l, row = idx >> 3, j0 = (idx & 7) * 8;
        size_t r = mb + row;
        f16x8 dt8 = *(const f16x8*)(dt16 + r * 2048 + d_base + j0);
        f16x8 xc8 = *(const f16x8*)(xc + r * 2048 + d_base + j0);
#pragma unroll
        for (int k = 0; k < 8; ++k) {
            union { f16x2 h2; float f; } u;
            u.h2[0] = dt8[k];
            u.h2[1] = (f16)((float)dt8[k] * (float)xc8[k]);
            du_s[row][j0 + k] = u.f;
        }
    }
#pragma unroll
    for (int i = 0; i < 2; ++i) {
        int idx = i * 64 + l, row = idx >> 2, s4 = (idx & 3) * 4;
        *(f32x4*)&bq_s[row][s4] = *(const f32x4*)(proj + (mb + row) * 128 + 64 + s4);
    }
    __syncthreads();

    float h[16];
#pragma unroll
    for (int i = 0; i < 16; ++i) h[i] = 0.f;
    float sdt = 0.f;
#pragma unroll 2
    for (int t = 0; t < CT; ++t) {
        union { float f; f16x2 h2; } u;
        u.f = du_s[t][l];
        float dtv = (float)u.h2[0], uv = (float)u.h2[1];
        sdt += dtv;
        f32x4 B0 = *(const f32x4*)&bq_s[t][0];
        f32x4 B1 = *(const f32x4*)&bq_s[t][4];
        f32x4 B2 = *(const f32x4*)&bq_s[t][8];
        f32x4 B3 = *(const f32x4*)&bq_s[t][12];
#pragma unroll
        for (int i = 0; i < 4; ++i) {
            h[i]      = fmaf(__builtin_amdgcn_exp2f(dtv * a[i]),      h[i],      uv * B0[i]);
            h[i + 4]  = fmaf(__builtin_amdgcn_exp2f(dtv * a[i + 4]),  h[i + 4],  uv * B1[i]);
            h[i + 8]  = fmaf(__builtin_amdgcn_exp2f(dtv * a[i + 8]),  h[i + 8],  uv * B2[i]);
            h[i + 12] = fmaf(__builtin_amdgcn_exp2f(dtv * a[i + 12]), h[i + 12], uv * B3[i]);
        }
    }
    const size_t base = (size_t)c * NSTATE + ((size_t)((b << 11) + d) << 4);
    f16x8 P0, P1, E0, E1;
#pragma unroll
    for (int i = 0; i < 8; ++i) {
        P0[i] = (f16)__builtin_amdgcn_exp2f(a[i] * sdt);
        P1[i] = (f16)__builtin_amdgcn_exp2f(a[i + 8] * sdt);
        E0[i] = (f16)h[i];
        E1[i] = (f16)h[i + 8];
    }
    *(f16x8*)(Pbuf + base) = P0;
    *(f16x8*)(Pbuf + base + 8) = P1;
    *(f16x8*)(Hend + base) = E0;
    *(f16x8*)(Hend + base + 8) = E1;
}

// Combine: f32 accumulation, f16 storage. 1 state per thread.
__global__ __launch_bounds__(256) void scan_combine(const f16* __restrict__ Pbuf, const f16* __restrict__ Hend,
                                                    f16* __restrict__ Hinit) {
    int s = blockIdx.x * 256 + threadIdx.x;  // grid 256 blocks, 65536 states
    float h = 0.f;
#pragma unroll
    for (int c = 0; c < NCHUNK; c++) {
        size_t o = (size_t)c * NSTATE + s;
        Hinit[o] = (f16)h;
        h = fmaf((float)Pbuf[o], h, (float)Hend[o]);
    }
}

__global__ __launch_bounds__(64) void scan_p2(const f16* __restrict__ dt16, const f16* __restrict__ xc,
                                              const f16* __restrict__ xz, const float* __restrict__ proj,
                                              const float* __restrict__ A_log, const float* __restrict__ Dp,
                                              const f16* __restrict__ Hinit, f16* __restrict__ y16) {
    __shared__ f32x2 dg_s[CT][64];  // {pack(dt,u), pack(silu(z), D*x*silu(z))}  16KB
    __shared__ float bq_s[CT][16];  // B natural  2KB
    __shared__ float cq_s[CT][16];  // C natural  2KB
    const int l = threadIdx.x;
    const int c = blockIdx.x, dgb = blockIdx.y, b = blockIdx.z;
    const int d_base = dgb << 6;
    const int d = d_base + l;
    const size_t mb = (size_t)b * 2048 + (size_t)c * CT;

    float a[16];
#pragma unroll
    for (int i = 0; i < 16; i += 4) {
        f32x4 av = *(const f32x4*)(A_log + (size_t)d * 16 + i);
#pragma unroll
        for (int k = 0; k < 4; ++k) a[i + k] = -fast_exp(av[k]) * LOG2E;
    }
    // staging
#pragma unroll
    for (int i = 0; i < 4; ++i) {
        int idx = i * 64 + l, row = idx >> 3, j0 = (idx & 7) * 8;
        size_t r = mb + row;
        f16x8 dt8 = *(const f16x8*)(dt16 + r * 2048 + d_base + j0);
        f16x8 xc8 = *(const f16x8*)(xc + r * 2048 + d_base + j0);
        f16x8 xz8 = *(const f16x8*)(xz + r * 4096 + 2048 + d_base + j0);
        f32x4 dv0 = *(const f32x4*)(Dp + d_base + j0);
        f32x4 dv1 = *(const f32x4*)(Dp + d_base + j0 + 4);
#pragma unroll
        for (int k = 0; k < 8; ++k) {
            float dtv = (float)dt8[k], xv = (float)xc8[k];
            union { f16x2 h2; float f; } u;
            u.h2[0] = dt8[k];
            u.h2[1] = (f16)(dtv * xv);
            float sz = silu_f((float)xz8[k]);
            float Dv = (k < 4) ? dv0[k & 3] : dv1[k & 3];
            union { f16x2 h2; float f; } v;
            v.h2[0] = (f16)sz;
            v.h2[1] = (f16)(Dv * xv * sz);
            dg_s[row][j0 + k] = (f32x2){u.f, v.f};
        }
    }
#pragma unroll
    for (int i = 0; i < 2; ++i) {
        int idx = i * 64 + l, row = idx >> 2, s4 = (idx & 3) * 4;
        *(f32x4*)&bq_s[row][s4] = *(const f32x4*)(proj + (mb + row) * 128 + 64 + s4);
        *(f32x4*)&cq_s[row][s4] = *(const f32x4*)(proj + (mb + row) * 128 + 80 + s4);
    }
    const size_t base = (size_t)c * NSTATE + ((size_t)((b << 11) + d) << 4);
    f16x8 H0 = *(const f16x8*)(Hinit + base);
    f16x8 H1 = *(const f16x8*)(Hinit + base + 8);
    float h[16];
#pragma unroll
    for (int i = 0; i < 8; ++i) { h[i] = (float)H0[i]; h[i + 8] = (float)H1[i]; }
    __syncthreads();

#pragma unroll 2
    for (int t = 0; t < CT; ++t) {
        f32x2 dgv = dg_s[t][l];
        union { float f; f16x2 h2; } u;
        u.f = dgv[0];
        float dtv = (float)u.h2[0], uv = (float)u.h2[1];
        f32x4 B0 = *(const f32x4*)&bq_s[t][0];
        f32x4 B1 = *(const f32x4*)&bq_s[t][4];
        f32x4 B2 = *(const f32x4*)&bq_s[t][8];
        f32x4 B3 = *(const f32x4*)&bq_s[t][12];
        f32x4 C0 = *(const f32x4*)&cq_s[t][0];
        f32x4 C1 = *(const f32x4*)&cq_s[t][4];
        f32x4 C2 = *(const f32x4*)&cq_s[t][8];
        f32x4 C3 = *(const f32x4*)&cq_s[t][12];
        float yp0 = 0.f, yp1 = 0.f, yp2 = 0.f, yp3 = 0.f;
#pragma unroll
        for (int i = 0; i < 4; ++i) {
            h[i]      = fmaf(__builtin_amdgcn_exp2f(dtv * a[i]),      h[i],      uv * B0[i]);
            h[i + 4]  = fmaf(__builtin_amdgcn_exp2f(dtv * a[i + 4]),  h[i + 4],  uv * B1[i]);
            h[i + 8]  = fmaf(__builtin_amdgcn_exp2f(dtv * a[i + 8]),  h[i + 8],  uv * B2[i]);
            h[i + 12] = fmaf(__builtin_amdgcn_exp2f(dtv * a[i + 12]), h[i + 12], uv * B3[i]);
            yp0 = fmaf(h[i], C0[i], yp0);
            yp1 = fmaf(h[i + 4], C1[i], yp1);
            yp2 = fmaf(h[i + 8], C2[i], yp2);
            yp3 = fmaf(h[i + 12], C3[i], yp3);
        }
        float yp = (yp0 + yp1) + (yp2 + yp3);
        union { float f; f16x2 h2; } v;
        v.f = dgv[1];
        float yv = fmaf(yp, (float)v.h2[0], (float)v.h2[1]);
        y16[(mb + t) * 2048 + d] = (f16)yv;  // 64 contiguous f16 per wave
    }
}

extern "C" void kernel_launch(void* const* d_in, const int* in_sizes, int n_in,
                              void* d_out, int out_size, void* d_ws, size_t ws_size,
                              hipStream_t stream) {
    const float* hidden = (const float*)d_in[0];
    const float* W_in   = (const float*)d_in[1];
    const float* conv_w = (const float*)d_in[2];
    const float* conv_b = (const float*)d_in[3];
    const float* W_x    = (const float*)d_in[4];
    const float* W_dt   = (const float*)d_in[5];
    const float* b_dt   = (const float*)d_in[6];
    const float* A_log  = (const float*)d_in[7];
    const float* D_par  = (const float*)d_in[8];
    const float* W_out  = (const float*)d_in[9];
    float* out = (float*)d_out;

    char* ws = (char*)d_ws;
    size_t off = 0;
    auto alloc = [&](size_t bytes) { void* p = ws + off; off += (bytes + 255) & ~(size_t)255; return p; };
    f16* h16     = (f16*)alloc(4096ull * 1024 * 2);   // dead after in_proj -> Pbuf16
    f16* Win16   = (f16*)alloc(4096ull * 1024 * 2);   // dead after in_proj -> Hinit16
    f16* Wx16    = (f16*)alloc(128ull * 2048 * 2);
    f16* Wdt16   = (f16*)alloc(2048ull * 64 * 2);
    f16* Wout16  = (f16*)alloc(1024ull * 2048 * 2);
    f16* xz16    = (f16*)alloc(4096ull * 4096 * 2);
    f16* xc16    = (f16*)alloc(4096ull * 2048 * 2);
    float* proj  = (float*)alloc(4096ull * 128 * 4);
    f16* dtlo16  = (f16*)alloc(4096ull * 64 * 2);
    f16* dt16    = (f16*)alloc(4096ull * 2048 * 2);
    f16* y16     = (f16*)alloc(4096ull * 2048 * 2);   // 16.78MB
    // aliases (timeline-checked):
    f16* Pws     = (f16*)y16;     // f16 split-K partials (8.4MB): written/read before scan_p1
    f16* Pbuf16  = (f16*)h16;     // 8.39MB (h16 dead after in_proj)
    f16* Hend16  = (f16*)y16;     // 8.39MB; written by p1, read by combine, y16 rewritten in p2
    f16* Hinit16 = (f16*)Win16;   // 8.39MB (Win16 dead after in_proj)
    (void)ws_size; (void)in_sizes; (void)n_in; (void)out_size;

    // fused f32->f16 operand prep (one launch)
    cvt_all<<<10624, 256, 0, stream>>>(hidden, W_in, W_out, W_dt, W_x,
                                       h16, Win16, Wout16, Wdt16, Wx16);

    // in_proj: xz = hidden @ W_in^T   (4096 x 4096 x 1024) -- 16-wave gemm256
    gemm256<<<dim3(16, 16), 1024, 0, stream>>>(h16, Win16, xz16, 4096, 1024);
    // depthwise conv + SiLU (4 timesteps/thread)
    conv_silu_k<<<1024, 256, 0, stream>>>(xz16, conv_w, conv_b, xc16);
    // x_proj with split-K=8: Pws[z] = xc @ Wx^T over K-slice z (f16 partials)
    gemm_gl<0, f16><<<dim3(1, 32, 8), 256, 0, stream>>>(xc16, Wx16, Pws, nullptr, 4096, 128, 2048, 256);
    reduce_proj<<<512, 256, 0, stream>>>(Pws, proj, dtlo16);
    // dt = softplus(dtlo @ W_dt^T + b_dt) -> f16
    gemm_gl<1, f16><<<dim3(16, 32, 1), 256, 0, stream>>>(dtlo16, Wdt16, dt16, b_dt, 4096, 2048, 64, 64);
    // chunked selective scan + gating -> y16 (1 lane = 1 chain)
    scan_p1<<<dim3(NCHUNK, 32, 2), 64, 0, stream>>>(dt16, xc16, proj, A_log, Pbuf16, Hend16);
    scan_combine<<<256, 256, 0, stream>>>(Pbuf16, Hend16, Hinit16);
    scan_p2<<<dim3(NCHUNK, 32, 2), 64, 0, stream>>>(dt16, xc16, xz16, proj, A_log, D_par, Hinit16, y16);
    // out_proj: out = y @ W_out^T (BK=32 ring-4, 2 blocks/CU)
    gemm_o32<<<dim3(8, 32), 512, 0, stream>>>(y16, Wout16, out, 1024, 2048);
}